// Round 9
// baseline (13589.413 us; speedup 1.0000x reference)
//
#include <hip/hip_runtime.h>

#define BATCH 32
#define NPTS  8192
#define DIM   64
#define KC    128
#define NITER 10
#define LN_EPS 1e-5f

#define BLKS_PER_B  32   // 256 points per block
#define NBLK        (BATCH * BLKS_PER_B)   // 1024

// ---------------------------------------------------------------------------
// R8 lesson: read-only register arrays (x or c rows) ALWAYS get sunk/remat'd
// by the RA. Accumulators cannot be. So: register-tiled GEMM — thread owns a
// 4-point x 8-cluster dot-accumulator tile (32 VGPRs, loop-carried), streams
// x and c float4 chunks from global per d-step (L1/L2-hot, 12 loads : 128
// FMA). No LDS operand staging; LDS holds only the R6-proven accumulator.
//
// Thread map: g = tid>>4 owns points {p0..p0+3}; kg = tid&15 owns
// k in {kg, kg+16, ..., kg+112} (strided-16 so each point's 128 distances
// live in one aligned 16-lane group).
//
// Correctness invariants:
//  * d = (x2 + c2[k]) - 2*dot in fp32 (exact cancellation form, unchanged).
//  * dot: fp32 FMA chain, chunk-nested .x.y.z.w, j ascending (single chain).
//    np/BLAS, jax/XLA and R3's 4-chain are already three mutually-different
//    dot orders agreeing to ~4e-3: the correlated class is set by the
//    FORMULA (exact cancellation), not the dot order.
//  * argmin: in-thread k-ascending strict-<, then (d,k)-lex 16-lane butterfly
//    == exact serial first-index.
//  * center sums: f32 LDS atomics + per-block flush + fp64 reduce (R6-proven
//    replay-stable).
//
// d_out doubles as storage: centers region = cen; soft region temporarily
// holds per-block partials (fully overwritten by final_kernel).
// ws: xn fp32 (64MB) | xsq fp32 (1MB) | c2 fp32 (16KB)
// ---------------------------------------------------------------------------

__global__ __launch_bounds__(256) void ln_kernel(const float* __restrict__ patches,
                                                 const float* __restrict__ gamma,
                                                 const float* __restrict__ beta,
                                                 float* __restrict__ xn,
                                                 float* __restrict__ cen,
                                                 float* __restrict__ c2) {
    int row = blockIdx.x * 4 + (threadIdx.x >> 6);
    int lane = threadIdx.x & 63;
    size_t base = (size_t)row * DIM + lane;
    float x = patches[base];

    float s = x;
#pragma unroll
    for (int m = 32; m >= 1; m >>= 1) s += __shfl_xor(s, m, 64);
    float mu = s * (1.0f / 64.0f);
    float dx = x - mu;

    float v = dx * dx;
#pragma unroll
    for (int m = 32; m >= 1; m >>= 1) v += __shfl_xor(v, m, 64);
    float var = v * (1.0f / 64.0f);

    float val = dx * (1.0f / sqrtf(var + LN_EPS)) * gamma[lane] + beta[lane];
    xn[base] = val;

    int n = row & (NPTS - 1);
    int b = row >> 13;  // NPTS = 8192 = 2^13
    if (n < KC) {
        cen[((size_t)(b * KC + n)) * DIM + lane] = val;
        float q = val * val;
#pragma unroll
        for (int m = 32; m >= 1; m >>= 1) q += __shfl_xor(q, m, 64);
        if (lane == 0) c2[b * KC + n] = q;
    }
}

__global__ __launch_bounds__(256) void xsq_kernel(const float* __restrict__ xn,
                                                  float* __restrict__ xsq) {
    int p = blockIdx.x * 256 + threadIdx.x;
    const float4* xp = (const float4*)(xn + (size_t)p * DIM);
    float a0 = 0.f, a1 = 0.f, a2 = 0.f, a3 = 0.f;
#pragma unroll
    for (int j = 0; j < 16; ++j) {
        float4 t = xp[j];
        a0 = fmaf(t.x, t.x, a0);
        a1 = fmaf(t.y, t.y, a1);
        a2 = fmaf(t.z, t.z, a2);
        a3 = fmaf(t.w, t.w, a3);
    }
    xsq[p] = (a0 + a1) + (a2 + a3);
}

// Register-tiled dot core: acc[pi][ki] += x4[p0+pi][j] . c4[kg+16ki][j]
#define DOT_TILE_BODY()                                                     \
    float acc[4][8];                                                        \
    _Pragma("unroll")                                                       \
    for (int pi = 0; pi < 4; ++pi)                                          \
        _Pragma("unroll")                                                   \
        for (int ki = 0; ki < 8; ++ki) acc[pi][ki] = 0.f;                   \
    _Pragma("unroll")                                                       \
    for (int j = 0; j < 16; ++j) {                                          \
        float4 xv[4];                                                       \
        _Pragma("unroll")                                                   \
        for (int pi = 0; pi < 4; ++pi)                                      \
            xv[pi] = ((const float4*)(xn + (size_t)(p0 + pi) * DIM))[j];    \
        _Pragma("unroll")                                                   \
        for (int ki = 0; ki < 8; ++ki) {                                    \
            float4 cv = ((const float4*)(cb + (size_t)(kg + 16 * ki) * DIM))[j]; \
            _Pragma("unroll")                                               \
            for (int pi = 0; pi < 4; ++pi) {                                \
                acc[pi][ki] = fmaf(xv[pi].w, cv.w, fmaf(xv[pi].z, cv.z,     \
                              fmaf(xv[pi].y, cv.y,                          \
                              fmaf(xv[pi].x, cv.x, acc[pi][ki]))));         \
            }                                                               \
        }                                                                   \
    }

__global__ __launch_bounds__(256) void assign_kernel(const float* __restrict__ xn,
                                                     const float* __restrict__ xsq,
                                                     const float* __restrict__ cen,
                                                     const float* __restrict__ c2,
                                                     float* __restrict__ part,
                                                     float* __restrict__ cntpart) {
    __shared__ float accf[KC * 65];
    __shared__ float cntf[KC];
    int tid = threadIdx.x;
    for (int i = tid; i < KC * 65; i += 256) accf[i] = 0.f;
    if (tid < KC) cntf[tid] = 0.f;
    __syncthreads();

    int blk = blockIdx.x, b = blk >> 5;
    int pblock = b * NPTS + (blk & 31) * 256;
    int g = tid >> 4, kg = tid & 15;

    const float* cb = cen + (size_t)b * KC * DIM;
    const float* c2p = c2 + b * KC;
    float c2r[8];
#pragma unroll
    for (int ki = 0; ki < 8; ++ki) c2r[ki] = c2p[kg + 16 * ki];

    for (int sub = 0; sub < 4; ++sub) {
        int p0 = pblock + sub * 64 + 4 * g;

        DOT_TILE_BODY();

#pragma unroll
        for (int pi = 0; pi < 4; ++pi) {
            int p = p0 + pi;
            float xq = xsq[p];
            float bd = 3.4e38f;
            int bk = KC - 1;
#pragma unroll
            for (int ki = 0; ki < 8; ++ki) {  // ki ascending == k ascending
                float d = (xq + c2r[ki]) - 2.0f * acc[pi][ki];
                if (d < bd) { bd = d; bk = kg + 16 * ki; }
            }
#pragma unroll
            for (int mm = 1; mm <= 8; mm <<= 1) {  // 16-lane group butterfly
                float od = __shfl_xor(bd, mm, 64);
                int ok = __shfl_xor(bk, mm, 64);
                if (od < bd || (od == bd && ok < bk)) { bd = od; bk = ok; }
            }
            // lane kg accumulates dims [4kg, 4kg+4) of point p (f32 atomics)
            float4 xv = ((const float4*)(xn + (size_t)p * DIM))[kg];
            float* dst = &accf[bk * 65 + 4 * kg];
            atomicAdd(dst + 0, xv.x);
            atomicAdd(dst + 1, xv.y);
            atomicAdd(dst + 2, xv.z);
            atomicAdd(dst + 3, xv.w);
            if (kg == 0) atomicAdd(&cntf[bk], 1.0f);
        }
    }
    __syncthreads();

    float* gp = part + (size_t)blk * (KC * DIM);
    for (int i = tid; i < KC * DIM; i += 256) {
        int k = i >> 6, d = i & 63;
        gp[i] = accf[k * 65 + d];
    }
    if (tid < KC) cntpart[blk * KC + tid] = cntf[tid];
}

__global__ __launch_bounds__(256) void update_kernel(const float* __restrict__ part,
                                                     const float* __restrict__ cntpart,
                                                     float* __restrict__ cen,
                                                     float* __restrict__ c2) {
    int row = blockIdx.x * 4 + (threadIdx.x >> 6);  // b*KC + k
    int lane = threadIdx.x & 63;
    int b = row >> 7;
    int k = row & (KC - 1);

    double s = 0.0;
    float cnt = 0.f;
#pragma unroll
    for (int sub = 0; sub < BLKS_PER_B; ++sub) {
        s += (double)part[((size_t)(b * BLKS_PER_B + sub)) * (KC * DIM) + (size_t)k * DIM + lane];
        cnt += cntpart[(b * BLKS_PER_B + sub) * KC + k];
    }

    size_t idx = (size_t)row * DIM + lane;
    float old = cen[idx];
    float nc = (cnt > 0.f) ? ((float)s / cnt) : old;
    cen[idx] = nc;

    float q = nc * nc;
#pragma unroll
    for (int m = 32; m >= 1; m >>= 1) q += __shfl_xor(q, m, 64);
    if (lane == 0) c2[row] = q;
}

__global__ __launch_bounds__(256) void final_kernel(const float* __restrict__ xn,
                                                    const float* __restrict__ xsq,
                                                    const float* __restrict__ cen,
                                                    const float* __restrict__ c2,
                                                    float* __restrict__ soft) {
    int tid = threadIdx.x;
    int blk = blockIdx.x, b = blk >> 5;
    int pblock = b * NPTS + (blk & 31) * 256;
    int g = tid >> 4, kg = tid & 15;

    const float* cb = cen + (size_t)b * KC * DIM;
    const float* c2p = c2 + b * KC;
    float c2r[8];
#pragma unroll
    for (int ki = 0; ki < 8; ++ki) c2r[ki] = c2p[kg + 16 * ki];

    for (int sub = 0; sub < 4; ++sub) {
        int p0 = pblock + sub * 64 + 4 * g;

        DOT_TILE_BODY();

#pragma unroll
        for (int pi = 0; pi < 4; ++pi) {
            int p = p0 + pi;
            float xq = xsq[p];
            float z[8];
#pragma unroll
            for (int ki = 0; ki < 8; ++ki)
                z[ki] = -((xq + c2r[ki]) - 2.0f * acc[pi][ki]);

            float m = z[0];
#pragma unroll
            for (int ki = 1; ki < 8; ++ki) m = fmaxf(m, z[ki]);
#pragma unroll
            for (int mm = 1; mm <= 8; mm <<= 1) m = fmaxf(m, __shfl_xor(m, mm, 64));

            float e[8];
            float s = 0.f;
#pragma unroll
            for (int ki = 0; ki < 8; ++ki) { e[ki] = __expf(z[ki] - m); s += e[ki]; }
#pragma unroll
            for (int mm = 1; mm <= 8; mm <<= 1) s += __shfl_xor(s, mm, 64);
            float rinv = 1.0f / s;

            float* op = soft + (size_t)p * KC;
#pragma unroll
            for (int ki = 0; ki < 8; ++ki) op[kg + 16 * ki] = e[ki] * rinv;
        }
    }
}

extern "C" void kernel_launch(void* const* d_in, const int* in_sizes, int n_in,
                              void* d_out, int out_size, void* d_ws, size_t ws_size,
                              hipStream_t stream) {
    (void)in_sizes; (void)n_in; (void)out_size; (void)ws_size;
    const float* patches = (const float*)d_in[0];
    const float* gamma = (const float*)d_in[1];
    const float* beta = (const float*)d_in[2];
    float* out = (float*)d_out;

    float* ws = (float*)d_ws;
    float* xn = ws;                                   // 16,777,216 f32
    float* xsq = xn + (size_t)BATCH * NPTS * DIM;     // 262,144 f32
    float* c2 = xsq + (size_t)BATCH * NPTS;           // 4,096 f32

    float* cen = out;                                 // centers live in d_out
    float* soft = out + (size_t)BATCH * KC * DIM;
    float* part = soft;                               // 1024*8192 f32 (temp)
    float* cntpart = part + (size_t)NBLK * KC * DIM;  // 1024*128 f32 (temp)

    ln_kernel<<<BATCH * NPTS / 4, 256, 0, stream>>>(patches, gamma, beta, xn, cen, c2);
    xsq_kernel<<<BATCH * NPTS / 256, 256, 0, stream>>>(xn, xsq);

    for (int it = 0; it < NITER; ++it) {
        assign_kernel<<<NBLK, 256, 0, stream>>>(xn, xsq, cen, c2, part, cntpart);
        update_kernel<<<BATCH * KC / 4, 256, 0, stream>>>(part, cntpart, cen, c2);
    }

    final_kernel<<<NBLK, 256, 0, stream>>>(xn, xsq, cen, c2, soft);
}

// Round 10
// 3049.807 us; speedup vs baseline: 4.4558x; 4.4558x over previous
//
#include <hip/hip_runtime.h>

#define BATCH 32
#define NPTS  8192
#define DIM   64
#define KC    128
#define NITER 10
#define LN_EPS 1e-5f

#define BLKS_PER_B  32   // 256 points per block
#define NBLK        (BATCH * BLKS_PER_B)   // 1024

// ---------------------------------------------------------------------------
// R9 lesson: never stream c from global per-k (re-reads 512MB/pass, HBM-bound
// across 8 non-coherent XCD L2s). R8 lesson: ordinary loads of read-only
// arrays get rematerialized (VGPR=80). Fix: R7/R8 wave-shape (lane owns 2
// clusters, x streams wave-uniform) + c-tile staged in LDS once + per-lane
// VOLATILE reads into 32 float4 locals — volatile loads cannot be re-executed,
// so the RA must keep c resident (~128 VGPRs). Inner loop: zero per-k memory.
//
// Correctness invariants (trajectory == passing R3..R9, absmax 0.00390625):
//  * d = (xq + c2[k]) - 2*dot, fp32; DOT chain order: 4 sub-chains by j&3,
//    .x.y.z.w nesting, (e0+e1)+(e2+e3)  [R7/R8-proven verbatim]
//  * argmin: 6-level (d,k)-lex butterfly == serial first-index [R7-proven]
//  * center sums: f32 LDS atomics + per-block flush + fp64 cross-block
//    reduce [R4/R6-proven replay-stable]
//
// d_out doubles as storage: centers region = cen; soft region temporarily
// holds per-block partials (fully overwritten by final_kernel).
// ws: xn fp32 (64MB) | xsq fp32 (1MB) | c2 fp32 (16KB)
// ---------------------------------------------------------------------------

// Per-lane c rows in registers; x from wave-uniform array. R7's DOT_SC order.
#define DOT_REG(res, c) do {                                                \
    float e0 = 0.f, e1 = 0.f, e2 = 0.f, e3 = 0.f;                           \
    _Pragma("unroll")                                                       \
    for (int j = 0; j < 16; ++j) {                                          \
        float t = (j & 3) == 0 ? e0 : (j & 3) == 1 ? e1                     \
                  : (j & 3) == 2 ? e2 : e3;                                 \
        t = fmaf(xs_[4 * j + 0], (c)[j].x, t);                              \
        t = fmaf(xs_[4 * j + 1], (c)[j].y, t);                              \
        t = fmaf(xs_[4 * j + 2], (c)[j].z, t);                              \
        t = fmaf(xs_[4 * j + 3], (c)[j].w, t);                              \
        if ((j & 3) == 0) e0 = t; else if ((j & 3) == 1) e1 = t;            \
        else if ((j & 3) == 2) e2 = t; else e3 = t;                         \
    }                                                                       \
    res = (e0 + e1) + (e2 + e3);                                            \
} while (0)

// Stage c-tile to LDS (coalesced), then volatile-read own 2 rows into regs.
#define STAGE_AND_PIN_C()                                                   \
    {                                                                       \
        const float4* src = (const float4*)(cen + (size_t)b * KC * DIM);    \
        float4* dst = (float4*)lds_c;                                       \
        _Pragma("unroll")                                                   \
        for (int j = 0; j < 8; ++j) dst[tid + 256 * j] = src[tid + 256 * j];\
    }                                                                       \
    __syncthreads();                                                        \
    int kA = lane, kB = lane + 64;                                          \
    float4 cA[16], cB[16];                                                  \
    {                                                                       \
        volatile const float* sa = lds_c + kA * DIM;                        \
        volatile const float* sb = lds_c + kB * DIM;                        \
        _Pragma("unroll")                                                   \
        for (int j = 0; j < 16; ++j) {                                      \
            cA[j] = make_float4(sa[4*j], sa[4*j+1], sa[4*j+2], sa[4*j+3]);  \
            cB[j] = make_float4(sb[4*j], sb[4*j+1], sb[4*j+2], sb[4*j+3]);  \
        }                                                                   \
    }                                                                       \
    float c2A = c2[b * KC + kA], c2B = c2[b * KC + kB]

#define LOAD_XS(xrow)                                                       \
    float xs_[64];                                                          \
    _Pragma("unroll")                                                       \
    for (int j = 0; j < 64; ++j) xs_[j] = (xrow)[j]

__global__ __launch_bounds__(256) void ln_kernel(const float* __restrict__ patches,
                                                 const float* __restrict__ gamma,
                                                 const float* __restrict__ beta,
                                                 float* __restrict__ xn,
                                                 float* __restrict__ cen,
                                                 float* __restrict__ c2) {
    int row = blockIdx.x * 4 + (threadIdx.x >> 6);
    int lane = threadIdx.x & 63;
    size_t base = (size_t)row * DIM + lane;
    float x = patches[base];

    float s = x;
#pragma unroll
    for (int m = 32; m >= 1; m >>= 1) s += __shfl_xor(s, m, 64);
    float mu = s * (1.0f / 64.0f);
    float dx = x - mu;

    float v = dx * dx;
#pragma unroll
    for (int m = 32; m >= 1; m >>= 1) v += __shfl_xor(v, m, 64);
    float var = v * (1.0f / 64.0f);

    float val = dx * (1.0f / sqrtf(var + LN_EPS)) * gamma[lane] + beta[lane];
    xn[base] = val;

    int n = row & (NPTS - 1);
    int b = row >> 13;  // NPTS = 8192 = 2^13
    if (n < KC) {
        cen[((size_t)(b * KC + n)) * DIM + lane] = val;
        float q = val * val;
#pragma unroll
        for (int m = 32; m >= 1; m >>= 1) q += __shfl_xor(q, m, 64);
        if (lane == 0) c2[b * KC + n] = q;
    }
}

__global__ __launch_bounds__(256) void xsq_kernel(const float* __restrict__ xn,
                                                  float* __restrict__ xsq) {
    int p = blockIdx.x * 256 + threadIdx.x;
    const float4* xp = (const float4*)(xn + (size_t)p * DIM);
    float a0 = 0.f, a1 = 0.f, a2 = 0.f, a3 = 0.f;
#pragma unroll
    for (int j = 0; j < 16; ++j) {
        float4 t = xp[j];
        a0 = fmaf(t.x, t.x, a0);
        a1 = fmaf(t.y, t.y, a1);
        a2 = fmaf(t.z, t.z, a2);
        a3 = fmaf(t.w, t.w, a3);
    }
    xsq[p] = (a0 + a1) + (a2 + a3);
}

__global__ __launch_bounds__(256, 2) void assign_kernel(const float* __restrict__ xn,
                                                        const float* __restrict__ xsq,
                                                        const float* __restrict__ cen,
                                                        const float* __restrict__ c2,
                                                        float* __restrict__ part,
                                                        float* __restrict__ cntpart) {
    __shared__ float lds_c[KC * DIM];   // 32 KB c-tile
    __shared__ float accf[KC * 65];     // 33.25 KB accumulator (pad 65)
    __shared__ float cntf[KC];

    int tid = threadIdx.x;
    int lane = tid & 63;
    int wv = __builtin_amdgcn_readfirstlane(tid >> 6);
    int blk = blockIdx.x, b = blk >> 5;
    int pbase = b * NPTS + ((blk & 31) << 8) + wv * 64;

    for (int i = tid; i < KC * 65; i += 256) accf[i] = 0.f;
    if (tid < KC) cntf[tid] = 0.f;

    STAGE_AND_PIN_C();   // includes the needed __syncthreads()

    for (int i = 0; i < 64; ++i) {
        int p = pbase + i;
        const float* xrow = xn + (size_t)p * DIM;   // wave-uniform
        LOAD_XS(xrow);
        float xq = xsq[p];

        float dA, dB;
        DOT_REG(dA, cA);
        DOT_REG(dB, cB);
        float distA = (xq + c2A) - 2.0f * dA;
        float distB = (xq + c2B) - 2.0f * dB;

        float bd = distA; int bk = kA;
        if (distB < bd) { bd = distB; bk = kB; }   // kA < kB: first-index
#pragma unroll
        for (int mm = 1; mm <= 32; mm <<= 1) {
            float od = __shfl_xor(bd, mm, 64);
            int ok = __shfl_xor(bk, mm, 64);
            if (od < bd || (od == bd && ok < bk)) { bd = od; bk = ok; }
        }

        // lane contributes dim=lane of point p (f32 LDS atomics, proven)
        float xv = xrow[lane];
        atomicAdd(&accf[bk * 65 + lane], xv);
        if (lane == 0) atomicAdd(&cntf[bk], 1.0f);
    }
    __syncthreads();

    float* gp = part + (size_t)blk * (KC * DIM);
    for (int i = tid; i < KC * DIM; i += 256) {
        int k = i >> 6, d = i & 63;
        gp[i] = accf[k * 65 + d];
    }
    if (tid < KC) cntpart[blk * KC + tid] = cntf[tid];
}

__global__ __launch_bounds__(256) void update_kernel(const float* __restrict__ part,
                                                     const float* __restrict__ cntpart,
                                                     float* __restrict__ cen,
                                                     float* __restrict__ c2) {
    int row = blockIdx.x * 4 + (threadIdx.x >> 6);  // b*KC + k
    int lane = threadIdx.x & 63;
    int b = row >> 7;
    int k = row & (KC - 1);

    double s = 0.0;
    float cnt = 0.f;
#pragma unroll
    for (int sub = 0; sub < BLKS_PER_B; ++sub) {
        s += (double)part[((size_t)(b * BLKS_PER_B + sub)) * (KC * DIM) + (size_t)k * DIM + lane];
        cnt += cntpart[(b * BLKS_PER_B + sub) * KC + k];
    }

    size_t idx = (size_t)row * DIM + lane;
    float old = cen[idx];
    float nc = (cnt > 0.f) ? ((float)s / cnt) : old;
    cen[idx] = nc;

    float q = nc * nc;
#pragma unroll
    for (int m = 32; m >= 1; m >>= 1) q += __shfl_xor(q, m, 64);
    if (lane == 0) c2[row] = q;
}

// One distance pass; z held per-lane; butterfly max+sum; 2x256B stores/point.
__global__ __launch_bounds__(256, 2) void final_kernel(const float* __restrict__ xn,
                                                       const float* __restrict__ xsq,
                                                       const float* __restrict__ cen,
                                                       const float* __restrict__ c2,
                                                       float* __restrict__ soft) {
    __shared__ float lds_c[KC * DIM];   // 32 KB c-tile

    int tid = threadIdx.x;
    int lane = tid & 63;
    int wv = __builtin_amdgcn_readfirstlane(tid >> 6);
    int blk = blockIdx.x, b = blk >> 5;
    int pbase = b * NPTS + ((blk & 31) << 8) + wv * 64;

    STAGE_AND_PIN_C();

    for (int i = 0; i < 64; ++i) {
        int p = pbase + i;
        const float* xrow = xn + (size_t)p * DIM;
        LOAD_XS(xrow);
        float xq = xsq[p];

        float dA, dB;
        DOT_REG(dA, cA);
        DOT_REG(dB, cB);
        float zA = -((xq + c2A) - 2.0f * dA);
        float zB = -((xq + c2B) - 2.0f * dB);

        float m = fmaxf(zA, zB);
#pragma unroll
        for (int mm = 1; mm <= 32; mm <<= 1) m = fmaxf(m, __shfl_xor(m, mm, 64));

        float eA = __expf(zA - m), eB = __expf(zB - m);
        float s = eA + eB;
#pragma unroll
        for (int mm = 1; mm <= 32; mm <<= 1) s += __shfl_xor(s, mm, 64);
        float rinv = 1.0f / s;

        float* op = soft + (size_t)p * KC;
        op[lane] = eA * rinv;
        op[64 + lane] = eB * rinv;
    }
}

extern "C" void kernel_launch(void* const* d_in, const int* in_sizes, int n_in,
                              void* d_out, int out_size, void* d_ws, size_t ws_size,
                              hipStream_t stream) {
    (void)in_sizes; (void)n_in; (void)out_size; (void)ws_size;
    const float* patches = (const float*)d_in[0];
    const float* gamma = (const float*)d_in[1];
    const float* beta = (const float*)d_in[2];
    float* out = (float*)d_out;

    float* ws = (float*)d_ws;
    float* xn = ws;                                   // 16,777,216 f32
    float* xsq = xn + (size_t)BATCH * NPTS * DIM;     // 262,144 f32
    float* c2 = xsq + (size_t)BATCH * NPTS;           // 4,096 f32

    float* cen = out;                                 // centers live in d_out
    float* soft = out + (size_t)BATCH * KC * DIM;
    float* part = soft;                               // 1024*8192 f32 (temp)
    float* cntpart = part + (size_t)NBLK * KC * DIM;  // 1024*128 f32 (temp)

    ln_kernel<<<BATCH * NPTS / 4, 256, 0, stream>>>(patches, gamma, beta, xn, cen, c2);
    xsq_kernel<<<BATCH * NPTS / 256, 256, 0, stream>>>(xn, xsq);

    for (int it = 0; it < NITER; ++it) {
        assign_kernel<<<NBLK, 256, 0, stream>>>(xn, xsq, cen, c2, part, cntpart);
        update_kernel<<<BATCH * KC / 4, 256, 0, stream>>>(part, cntpart, cen, c2);
    }

    final_kernel<<<NBLK, 256, 0, stream>>>(xn, xsq, cen, c2, soft);
}

// Round 11
// 2523.991 us; speedup vs baseline: 5.3841x; 1.2083x over previous
//
#include <hip/hip_runtime.h>

#define BATCH 32
#define NPTS  8192
#define DIM   64
#define KC    128
#define NITER 10
#define LN_EPS 1e-5f

#define BLKS_PER_B  32   // 256 points per block
#define NBLK        (BATCH * BLKS_PER_B)   // 1024

// ---------------------------------------------------------------------------
// R10 lesson (the big one): the compiler may re-read any operand from a
// source it can prove unchanged (LDS or global) instead of keeping it in
// VGPRs — volatile/asm tricks don't help. To force residency, DESTROY the
// source after reading it: we read c rows into registers, then ZERO the same
// LDS region to become the accumulator. After that barrier the register
// copies are the only live copies; the RA must keep them (~170 VGPR < 256
// cap from __launch_bounds__(256,2)).
//
// Shape (R7/R10-proven): lane owns clusters {lane, lane+64}; x rows stream
// wave-uniform (s_load, scalar pipe); inner loop has ZERO per-k memory ops.
//
// Correctness invariants (trajectory == passing R3..R10, absmax 0.00390625):
//  * d = (xq + c2[k]) - 2*dot, fp32; DOT: 4 sub-chains by j&3, .x.y.z.w
//    nesting, (e0+e1)+(e2+e3)  [R7/R10-proven verbatim]
//  * argmin: 6-level (d,k)-lex butterfly == serial first-index [R7-proven]
//  * center sums: f32 LDS atomics + per-block flush + fp64 cross-block
//    reduce [R4/R6/R10-proven replay-stable]
//
// d_out doubles as storage: centers region = cen; soft region temporarily
// holds per-block partials (fully overwritten by final_kernel).
// ws: xn fp32 (64MB) | xsq fp32 (1MB) | c2 fp32 (16KB)
// ---------------------------------------------------------------------------

// Per-lane c rows in registers; x from wave-uniform array. R7's DOT order.
#define DOT_REG(res, c) do {                                                \
    float e0 = 0.f, e1 = 0.f, e2 = 0.f, e3 = 0.f;                           \
    _Pragma("unroll")                                                       \
    for (int j = 0; j < 16; ++j) {                                          \
        float t = (j & 3) == 0 ? e0 : (j & 3) == 1 ? e1                     \
                  : (j & 3) == 2 ? e2 : e3;                                 \
        t = fmaf(xs_[4 * j + 0], (c)[j].x, t);                              \
        t = fmaf(xs_[4 * j + 1], (c)[j].y, t);                              \
        t = fmaf(xs_[4 * j + 2], (c)[j].z, t);                              \
        t = fmaf(xs_[4 * j + 3], (c)[j].w, t);                              \
        if ((j & 3) == 0) e0 = t; else if ((j & 3) == 1) e1 = t;            \
        else if ((j & 3) == 2) e2 = t; else e3 = t;                         \
    }                                                                       \
    res = (e0 + e1) + (e2 + e3);                                            \
} while (0)

// Stage c-tile into lds (coalesced), read own 2 rows to registers, then the
// CALLER zeroes/overwrites lds — destroying the source and pinning the regs.
#define STAGE_READ_C(ldsbuf)                                                \
    {                                                                       \
        const float4* src = (const float4*)(cen + (size_t)b * KC * DIM);    \
        float4* dst = (float4*)(ldsbuf);                                    \
        _Pragma("unroll")                                                   \
        for (int j = 0; j < 8; ++j) dst[tid + 256 * j] = src[tid + 256 * j];\
    }                                                                       \
    __syncthreads();                                                        \
    int kA = lane, kB = lane + 64;                                          \
    float4 cA[16], cB[16];                                                  \
    {                                                                       \
        const float4* sa = (const float4*)((ldsbuf) + kA * DIM);            \
        const float4* sb = (const float4*)((ldsbuf) + kB * DIM);            \
        _Pragma("unroll")                                                   \
        for (int j = 0; j < 16; ++j) { cA[j] = sa[j]; cB[j] = sb[j]; }      \
    }                                                                       \
    __syncthreads();                                                        \
    float c2A = c2[b * KC + kA], c2B = c2[b * KC + kB]

#define LOAD_XS(xrow)                                                       \
    float xs_[64];                                                          \
    _Pragma("unroll")                                                       \
    for (int j = 0; j < 64; ++j) xs_[j] = (xrow)[j]

__global__ __launch_bounds__(256) void ln_kernel(const float* __restrict__ patches,
                                                 const float* __restrict__ gamma,
                                                 const float* __restrict__ beta,
                                                 float* __restrict__ xn,
                                                 float* __restrict__ cen,
                                                 float* __restrict__ c2) {
    int row = blockIdx.x * 4 + (threadIdx.x >> 6);
    int lane = threadIdx.x & 63;
    size_t base = (size_t)row * DIM + lane;
    float x = patches[base];

    float s = x;
#pragma unroll
    for (int m = 32; m >= 1; m >>= 1) s += __shfl_xor(s, m, 64);
    float mu = s * (1.0f / 64.0f);
    float dx = x - mu;

    float v = dx * dx;
#pragma unroll
    for (int m = 32; m >= 1; m >>= 1) v += __shfl_xor(v, m, 64);
    float var = v * (1.0f / 64.0f);

    float val = dx * (1.0f / sqrtf(var + LN_EPS)) * gamma[lane] + beta[lane];
    xn[base] = val;

    int n = row & (NPTS - 1);
    int b = row >> 13;  // NPTS = 8192 = 2^13
    if (n < KC) {
        cen[((size_t)(b * KC + n)) * DIM + lane] = val;
        float q = val * val;
#pragma unroll
        for (int m = 32; m >= 1; m >>= 1) q += __shfl_xor(q, m, 64);
        if (lane == 0) c2[b * KC + n] = q;
    }
}

__global__ __launch_bounds__(256) void xsq_kernel(const float* __restrict__ xn,
                                                  float* __restrict__ xsq) {
    int p = blockIdx.x * 256 + threadIdx.x;
    const float4* xp = (const float4*)(xn + (size_t)p * DIM);
    float a0 = 0.f, a1 = 0.f, a2 = 0.f, a3 = 0.f;
#pragma unroll
    for (int j = 0; j < 16; ++j) {
        float4 t = xp[j];
        a0 = fmaf(t.x, t.x, a0);
        a1 = fmaf(t.y, t.y, a1);
        a2 = fmaf(t.z, t.z, a2);
        a3 = fmaf(t.w, t.w, a3);
    }
    xsq[p] = (a0 + a1) + (a2 + a3);
}

__global__ __launch_bounds__(256, 2) void assign_kernel(const float* __restrict__ xn,
                                                        const float* __restrict__ xsq,
                                                        const float* __restrict__ cen,
                                                        const float* __restrict__ c2,
                                                        float* __restrict__ part,
                                                        float* __restrict__ cntpart) {
    // One region, two lives: c-tile staging (32KB), then accumulator+counts.
    __shared__ float lds[KC * 65 + KC];  // 33.75 KB

    int tid = threadIdx.x;
    int lane = tid & 63;
    int wv = __builtin_amdgcn_readfirstlane(tid >> 6);
    int blk = blockIdx.x, b = blk >> 5;
    int pbase = b * NPTS + ((blk & 31) << 8) + wv * 64;

    STAGE_READ_C(lds);

    // Destroy the staged c-tile: zero the region for its second life as the
    // accumulator. This is what pins cA/cB into VGPRs (no source remains).
    for (int i = tid; i < KC * 65 + KC; i += 256) lds[i] = 0.f;
    __syncthreads();
    float* accf = lds;
    float* cntf = lds + KC * 65;

    for (int i = 0; i < 64; ++i) {
        int p = pbase + i;
        const float* xrow = xn + (size_t)p * DIM;   // wave-uniform -> s_load
        LOAD_XS(xrow);
        float xq = xsq[p];

        float dA, dB;
        DOT_REG(dA, cA);
        DOT_REG(dB, cB);
        float distA = (xq + c2A) - 2.0f * dA;
        float distB = (xq + c2B) - 2.0f * dB;

        float bd = distA; int bk = kA;
        if (distB < bd) { bd = distB; bk = kB; }   // kA < kB: first-index
#pragma unroll
        for (int mm = 1; mm <= 32; mm <<= 1) {
            float od = __shfl_xor(bd, mm, 64);
            int ok = __shfl_xor(bk, mm, 64);
            if (od < bd || (od == bd && ok < bk)) { bd = od; bk = ok; }
        }

        // lane contributes dim=lane of point p (f32 LDS atomics, proven;
        // consecutive addresses -> 2 lanes/bank = conflict-free)
        float xv = xrow[lane];
        atomicAdd(&accf[bk * 65 + lane], xv);
        if (lane == 0) atomicAdd(&cntf[bk], 1.0f);
    }
    __syncthreads();

    float* gp = part + (size_t)blk * (KC * DIM);
    for (int i = tid; i < KC * DIM; i += 256) {
        int k = i >> 6, d = i & 63;
        gp[i] = accf[k * 65 + d];
    }
    if (tid < KC) cntpart[blk * KC + tid] = cntf[tid];
}

__global__ __launch_bounds__(256) void update_kernel(const float* __restrict__ part,
                                                     const float* __restrict__ cntpart,
                                                     float* __restrict__ cen,
                                                     float* __restrict__ c2) {
    int row = blockIdx.x * 4 + (threadIdx.x >> 6);  // b*KC + k
    int lane = threadIdx.x & 63;
    int b = row >> 7;
    int k = row & (KC - 1);

    double s = 0.0;
    float cnt = 0.f;
#pragma unroll
    for (int sub = 0; sub < BLKS_PER_B; ++sub) {
        s += (double)part[((size_t)(b * BLKS_PER_B + sub)) * (KC * DIM) + (size_t)k * DIM + lane];
        cnt += cntpart[(b * BLKS_PER_B + sub) * KC + k];
    }

    size_t idx = (size_t)row * DIM + lane;
    float old = cen[idx];
    float nc = (cnt > 0.f) ? ((float)s / cnt) : old;
    cen[idx] = nc;

    float q = nc * nc;
#pragma unroll
    for (int m = 32; m >= 1; m >>= 1) q += __shfl_xor(q, m, 64);
    if (lane == 0) c2[row] = q;
}

// One distance pass; z per-lane; butterfly max+sum; 2x256B stores/point.
__global__ __launch_bounds__(256, 2) void final_kernel(const float* __restrict__ xn,
                                                       const float* __restrict__ xsq,
                                                       const float* __restrict__ cen,
                                                       const float* __restrict__ c2,
                                                       float* __restrict__ soft) {
    __shared__ float lds[KC * DIM];   // 32 KB c-tile staging (then destroyed)

    int tid = threadIdx.x;
    int lane = tid & 63;
    int wv = __builtin_amdgcn_readfirstlane(tid >> 6);
    int blk = blockIdx.x, b = blk >> 5;
    int pbase = b * NPTS + ((blk & 31) << 8) + wv * 64;

    STAGE_READ_C(lds);

    // Destroy the source to pin cA/cB in registers.
    for (int i = tid; i < KC * DIM; i += 256) lds[i] = 0.f;
    __syncthreads();

    for (int i = 0; i < 64; ++i) {
        int p = pbase + i;
        const float* xrow = xn + (size_t)p * DIM;
        LOAD_XS(xrow);
        float xq = xsq[p];

        float dA, dB;
        DOT_REG(dA, cA);
        DOT_REG(dB, cB);
        float zA = -((xq + c2A) - 2.0f * dA);
        float zB = -((xq + c2B) - 2.0f * dB);

        float m = fmaxf(zA, zB);
#pragma unroll
        for (int mm = 1; mm <= 32; mm <<= 1) m = fmaxf(m, __shfl_xor(m, mm, 64));

        float eA = __expf(zA - m), eB = __expf(zB - m);
        float s = eA + eB;
#pragma unroll
        for (int mm = 1; mm <= 32; mm <<= 1) s += __shfl_xor(s, mm, 64);
        float rinv = 1.0f / s;

        float* op = soft + (size_t)p * KC;
        op[lane] = eA * rinv;
        op[64 + lane] = eB * rinv;
    }
}

extern "C" void kernel_launch(void* const* d_in, const int* in_sizes, int n_in,
                              void* d_out, int out_size, void* d_ws, size_t ws_size,
                              hipStream_t stream) {
    (void)in_sizes; (void)n_in; (void)out_size; (void)ws_size;
    const float* patches = (const float*)d_in[0];
    const float* gamma = (const float*)d_in[1];
    const float* beta = (const float*)d_in[2];
    float* out = (float*)d_out;

    float* ws = (float*)d_ws;
    float* xn = ws;                                   // 16,777,216 f32
    float* xsq = xn + (size_t)BATCH * NPTS * DIM;     // 262,144 f32
    float* c2 = xsq + (size_t)BATCH * NPTS;           // 4,096 f32

    float* cen = out;                                 // centers live in d_out
    float* soft = out + (size_t)BATCH * KC * DIM;
    float* part = soft;                               // 1024*8192 f32 (temp)
    float* cntpart = part + (size_t)NBLK * KC * DIM;  // 1024*128 f32 (temp)

    ln_kernel<<<BATCH * NPTS / 4, 256, 0, stream>>>(patches, gamma, beta, xn, cen, c2);
    xsq_kernel<<<BATCH * NPTS / 256, 256, 0, stream>>>(xn, xsq);

    for (int it = 0; it < NITER; ++it) {
        assign_kernel<<<NBLK, 256, 0, stream>>>(xn, xsq, cen, c2, part, cntpart);
        update_kernel<<<BATCH * KC / 4, 256, 0, stream>>>(part, cntpart, cen, c2);
    }

    final_kernel<<<NBLK, 256, 0, stream>>>(xn, xsq, cen, c2, soft);
}